// Round 1
// baseline (1509.886 us; speedup 1.0000x reference)
//
#include <hip/hip_runtime.h>
#include <math.h>

#define NB 2048
#define NL 512
#define NJ 256

// One block per batch element b. 256 threads = 4 waves.
// Thread decomposition for the x sweeps: jq = tid & 63 owns j = 4*jq..4*jq+3
// (float4), ls = tid >> 6 strides the l dimension by 4.
__global__ __launch_bounds__(256) void tal_kernel(
    const float* __restrict__ x,      // (B, L, J)
    const float* __restrict__ w1,     // (1, L)
    const float* __restrict__ b1,     // (1, J)
    const float* __restrict__ w2,     // (J, L)
    const float* __restrict__ b2,     // (1, L)
    float* __restrict__ h_out,        // (B, J)
    float* __restrict__ attn_out)     // (B, L)
{
    const int b   = blockIdx.x;
    const int tid = threadIdx.x;
    const int jq  = tid & 63;
    const int ls  = tid >> 6;

    __shared__ float  s_w1[NL];
    __shared__ float  s_tmp1[NJ];
    __shared__ float  s_attn[NL];
    __shared__ float4 s_red[4][64];
    __shared__ float  s_wred[8];

    s_w1[tid]       = w1[tid];
    s_w1[tid + 256] = w1[tid + 256];
    __syncthreads();

    const float4* x4 = reinterpret_cast<const float4*>(x) + (size_t)b * (NL * NJ / 4);

    // ---- pass 1: tmp1[j] = sigmoid(sum_l w1[l]*x[b,l,j] + b1[j]) ----
    float4 acc = make_float4(0.f, 0.f, 0.f, 0.f);
    #pragma unroll 4
    for (int l = ls; l < NL; l += 4) {
        const float  w = s_w1[l];
        const float4 v = x4[l * 64 + jq];
        acc.x = fmaf(w, v.x, acc.x);
        acc.y = fmaf(w, v.y, acc.y);
        acc.z = fmaf(w, v.z, acc.z);
        acc.w = fmaf(w, v.w, acc.w);
    }
    s_red[ls][jq] = acc;
    __syncthreads();
    if (ls == 0) {
        const float4 a0 = s_red[0][jq];
        const float4 a1 = s_red[1][jq];
        const float4 a2 = s_red[2][jq];
        const float4 a3 = s_red[3][jq];
        float z0 = a0.x + a1.x + a2.x + a3.x + b1[jq * 4 + 0];
        float z1 = a0.y + a1.y + a2.y + a3.y + b1[jq * 4 + 1];
        float z2 = a0.z + a1.z + a2.z + a3.z + b1[jq * 4 + 2];
        float z3 = a0.w + a1.w + a2.w + a3.w + b1[jq * 4 + 3];
        s_tmp1[jq * 4 + 0] = 1.f / (1.f + expf(-z0));
        s_tmp1[jq * 4 + 1] = 1.f / (1.f + expf(-z1));
        s_tmp1[jq * 4 + 2] = 1.f / (1.f + expf(-z2));
        s_tmp1[jq * 4 + 3] = 1.f / (1.f + expf(-z3));
    }
    __syncthreads();

    // ---- pass 2: tmp2[l] = sigmoid(sum_j tmp1[j]*w2[j,l] + b2[l]) / sqrt(L) ----
    float t2[2];
    #pragma unroll
    for (int c = 0; c < 2; ++c) {
        const int l = tid + c * 256;
        float a2s = 0.f;
        #pragma unroll 4
        for (int j = 0; j < NJ; ++j)
            a2s = fmaf(s_tmp1[j], w2[j * NL + l], a2s);  // s_tmp1: broadcast; w2: coalesced
        a2s += b2[l];
        const float sg = 1.f / (1.f + expf(-a2s));
        t2[c] = sg * 0.04419417382415922f;   // 1/sqrt(512)
    }

    // ---- softmax over l (512 values, 2 per thread) ----
    float m = fmaxf(t2[0], t2[1]);
    #pragma unroll
    for (int mask = 32; mask >= 1; mask >>= 1)
        m = fmaxf(m, __shfl_xor(m, mask, 64));
    if ((tid & 63) == 0) s_wred[tid >> 6] = m;
    __syncthreads();
    m = fmaxf(fmaxf(s_wred[0], s_wred[1]), fmaxf(s_wred[2], s_wred[3]));

    const float e0 = expf(t2[0] - m);
    const float e1 = expf(t2[1] - m);
    float ss = e0 + e1;
    #pragma unroll
    for (int mask = 32; mask >= 1; mask >>= 1)
        ss += __shfl_xor(ss, mask, 64);
    if ((tid & 63) == 0) s_wred[4 + (tid >> 6)] = ss;
    __syncthreads();
    ss = s_wred[4] + s_wred[5] + s_wred[6] + s_wred[7];
    const float inv = 1.f / ss;

    const float at0 = e0 * inv;
    const float at1 = e1 * inv;
    s_attn[tid]       = at0;
    s_attn[tid + 256] = at1;
    attn_out[(size_t)b * NL + tid]       = at0;
    attn_out[(size_t)b * NL + tid + 256] = at1;
    __syncthreads();

    // ---- pass 3: h[j] = sum_l attn[l]*x[b,l,j] ----
    float4 hacc = make_float4(0.f, 0.f, 0.f, 0.f);
    #pragma unroll 4
    for (int l = ls; l < NL; l += 4) {
        const float  a = s_attn[l];
        const float4 v = x4[l * 64 + jq];
        hacc.x = fmaf(a, v.x, hacc.x);
        hacc.y = fmaf(a, v.y, hacc.y);
        hacc.z = fmaf(a, v.z, hacc.z);
        hacc.w = fmaf(a, v.w, hacc.w);
    }
    s_red[ls][jq] = hacc;
    __syncthreads();
    if (ls == 0) {
        const float4 a0 = s_red[0][jq];
        const float4 a1 = s_red[1][jq];
        const float4 a2 = s_red[2][jq];
        const float4 a3 = s_red[3][jq];
        float4 r;
        r.x = a0.x + a1.x + a2.x + a3.x;
        r.y = a0.y + a1.y + a2.y + a3.y;
        r.z = a0.z + a1.z + a2.z + a3.z;
        r.w = a0.w + a1.w + a2.w + a3.w;
        reinterpret_cast<float4*>(h_out)[(size_t)b * 64 + jq] = r;
    }
}

extern "C" void kernel_launch(void* const* d_in, const int* in_sizes, int n_in,
                              void* d_out, int out_size, void* d_ws, size_t ws_size,
                              hipStream_t stream) {
    const float* x  = (const float*)d_in[0];
    const float* w1 = (const float*)d_in[1];
    const float* b1 = (const float*)d_in[2];
    const float* w2 = (const float*)d_in[3];
    const float* b2 = (const float*)d_in[4];

    float* h_out    = (float*)d_out;                       // (B, J)
    float* attn_out = h_out + (size_t)NB * NJ;             // (B, L)

    tal_kernel<<<NB, 256, 0, stream>>>(x, w1, b1, w2, b2, h_out, attn_out);
}